// Round 6
// baseline (145.574 us; speedup 1.0000x reference)
//
#include <hip/hip_runtime.h>
#include <hip/hip_bf16.h>

// PolymorphicSNN: reference collapses to
//   out[:, :256]     = heaviside(x @ W_lin.T + b_lin - 1.0)
//   out[:, 256:8448] = 0    (spk_mode == 0 identically since reg_out in {0,1})
//
// Write-BW bound: 277 MB/call -> ~40 us floor at the harness's own fill rate.
//
// Round-3/5 lesson: BLOCK-level role split maps entire CUs to one role
// (blocks on a CU differ by 256 in blockIdx -> role bits collapse). So the
// role split is done at WAVE granularity inside each block: 2 waves fill,
// 2 waves GEMM. Balanced across XCDs/CUs by construction; block-parity flips
// wave roles so each SIMD gets 2 fill + 2 GEMM waves. GEMM waves' in-order
// vmcnt queue holds only W loads + 8 spike stores (never the 256 KB fill).

#define SNN_B 8192
#define SNN_N 256
#define SNN_P 32
#define SNN_ROW (SNN_N * (SNN_P + 1))   // 8448 floats per output row
#define SNN_TB 8                        // batch rows per block

__global__ __launch_bounds__(256) void polysnn_kernel(
    const float* __restrict__ x,      // [B, N]
    const float* __restrict__ W,      // [N, N] row n = weights for output col n
    const float* __restrict__ bias,   // [N]
    float* __restrict__ out)          // [B, 8448]
{
    __shared__ float xs[SNN_TB][SNN_N];

    const int tid  = threadIdx.x;
    const int row0 = blockIdx.x * SNN_TB;

    // All 4 waves cooperatively stage 8 x-rows (512 float4, 2 per thread).
    {
        const float4* x4  = reinterpret_cast<const float4*>(x + (size_t)row0 * SNN_N);
        float4*       xs4 = reinterpret_cast<float4*>(&xs[0][0]);
        xs4[tid]       = x4[tid];
        xs4[tid + 256] = x4[tid + 256];
    }
    __syncthreads();   // single barrier, all waves present; divergence after

    const int wave = tid >> 6;
    const int lane = tid & 63;
    const int half = wave >> 1;                 // 0 or 1: which wave of the pair
    const int p    = (blockIdx.x >> 8) & 1;     // co-resident blocks differ by 256
                                                // -> flip roles per SIMD for balance

    if ((wave & 1) == p) {
        // ---- FILL role (2 waves): zero the 8 rows' mixed region (256 KB). ----
        const int ft = half * 64 + lane;        // 0..127
        const float4 z = make_float4(0.f, 0.f, 0.f, 0.f);
        for (int r = 0; r < SNN_TB; ++r) {
            float4* o4 = reinterpret_cast<float4*>(out + (size_t)(row0 + r) * SNN_ROW + SNN_N);
#pragma unroll
            for (int i = 0; i < 16; ++i) {
                o4[ft + i * 128] = z;           // coalesced, 2048 B/wave/instr
            }
        }
        return;   // fill waves retire; stores drain in background
    }

    // ---- GEMM role (2 waves): thread owns cols t and t+128, 8 rows. ----
    const int t  = half * 64 + lane;            // 0..127
    const int n0 = t, n1 = t + 128;

    float acc0[SNN_TB], acc1[SNN_TB];
#pragma unroll
    for (int r = 0; r < SNN_TB; ++r) { acc0[r] = 0.f; acc1[r] = 0.f; }

    const float4* w40 = reinterpret_cast<const float4*>(W + (size_t)n0 * SNN_N);
    const float4* w41 = reinterpret_cast<const float4*>(W + (size_t)n1 * SNN_N);
    const float4* xs4 = reinterpret_cast<const float4*>(&xs[0][0]);

#pragma unroll 4
    for (int k4 = 0; k4 < SNN_N / 4; ++k4) {
        const float4 w0 = w40[k4];
        const float4 w1 = w41[k4];
#pragma unroll
        for (int r = 0; r < SNN_TB; ++r) {
            // wave-uniform address -> LDS broadcast ds_read_b128, conflict-free
            const float4 xr = xs4[r * (SNN_N / 4) + k4];
            acc0[r] = fmaf(w0.x, xr.x, acc0[r]);
            acc0[r] = fmaf(w0.y, xr.y, acc0[r]);
            acc0[r] = fmaf(w0.z, xr.z, acc0[r]);
            acc0[r] = fmaf(w0.w, xr.w, acc0[r]);
            acc1[r] = fmaf(w1.x, xr.x, acc1[r]);
            acc1[r] = fmaf(w1.y, xr.y, acc1[r]);
            acc1[r] = fmaf(w1.z, xr.z, acc1[r]);
            acc1[r] = fmaf(w1.w, xr.w, acc1[r]);
        }
    }

    const float b0 = bias[n0], b1 = bias[n1];
#pragma unroll
    for (int r = 0; r < SNN_TB; ++r) {
        const float h0 = acc0[r] + b0;
        const float h1 = acc1[r] + b1;
        float s0, s1;
        if (__builtin_expect(fabsf(h0 - 1.0f) < 1e-3f, 0)) {
            // Borderline (f32 accum error <= ~6e-5 << 1e-3): re-decide in f64.
            double a = (double)b0;
            const float* wr = W + (size_t)n0 * SNN_N;
            for (int k = 0; k < SNN_N; ++k) a += (double)wr[k] * (double)xs[r][k];
            s0 = (a > 1.0) ? 1.0f : 0.0f;
        } else s0 = (h0 > 1.0f) ? 1.0f : 0.0f;
        if (__builtin_expect(fabsf(h1 - 1.0f) < 1e-3f, 0)) {
            double a = (double)b1;
            const float* wr = W + (size_t)n1 * SNN_N;
            for (int k = 0; k < SNN_N; ++k) a += (double)wr[k] * (double)xs[r][k];
            s1 = (a > 1.0) ? 1.0f : 0.0f;
        } else s1 = (h1 > 1.0f) ? 1.0f : 0.0f;
        out[(size_t)(row0 + r) * SNN_ROW + n0] = s0;
        out[(size_t)(row0 + r) * SNN_ROW + n1] = s1;
    }
}

extern "C" void kernel_launch(void* const* d_in, const int* in_sizes, int n_in,
                              void* d_out, int out_size, void* d_ws, size_t ws_size,
                              hipStream_t stream) {
    const float* x     = (const float*)d_in[0];
    const float* W_lin = (const float*)d_in[1];
    const float* b_lin = (const float*)d_in[2];
    // d_in[3] (W_sel) and d_in[4] (b_sel) are dead: spk_mode == 0 identically.
    float* out = (float*)d_out;

    dim3 grid(SNN_B / SNN_TB);   // 1024 blocks, 4 waves each (2 fill + 2 gemm)
    dim3 block(256);
    polysnn_kernel<<<grid, block, 0, stream>>>(x, W_lin, b_lin, out);
}

// Round 7
// 72.798 us; speedup vs baseline: 1.9997x; 1.9997x over previous
//
#include <hip/hip_runtime.h>
#include <hip/hip_bf16.h>

// PolymorphicSNN: reference collapses to
//   out[:, :256]     = heaviside(x @ W_lin.T + b_lin - 1.0)
//   out[:, 256:8448] = 0    (spk_mode == 0 identically since reg_out in {0,1})
//
// Cost model (round 3/5/6 post-mortem — role splits all regressed):
//  (1) uncoalesced W loads (lane stride 1 KB = 64 lines/instr)  ~27 us/CU
//  (2) too many LDS broadcast reads (1 col/thread)              ~41 us/CU
//  (3) 268 MB zero-fill drain                                   ~39 us chip
// Fix: pre-transpose W into d_ws -> coalesced 16 B/lane W reads; 8x4
// register blocking (32 rows/block, 256 blocks = 1/CU); zero-fill stores
// interleaved INTO the k-loop behind prefetched W loads (stores never gate
// the compute's vmcnt wait); nontemporal stores keep zeros out of L2.

#define SNN_B 8192
#define SNN_N 256
#define SNN_P 32
#define SNN_ROW (SNN_N * (SNN_P + 1))   // 8448 floats per output row
#define BLK_ROWS 32                     // batch rows per block (8 per wave)

typedef float floatx4 __attribute__((ext_vector_type(4)));

// ---- Pre-pass: W_T[k][n] = W[n][k] (256x256) ----
__global__ __launch_bounds__(256) void w_transpose_kernel(
    const float* __restrict__ W, float* __restrict__ WT)
{
    const int o = blockIdx.x * 256 + threadIdx.x;   // 0..65535, coalesced write
    const int k = o >> 8, n = o & 255;
    WT[o] = W[n * SNN_N + k];
}

// ---- Main: GEMM + spikes + interleaved zero-fill ----
__global__ __launch_bounds__(256) void polysnn_main_kernel(
    const float* __restrict__ x,      // [B, N]
    const float* __restrict__ W,      // [N, N] original (borderline recheck only)
    const float* __restrict__ WT,     // [N, N] transposed: WT[k][n]
    const float* __restrict__ bias,   // [N]
    float* __restrict__ out)          // [B, 8448]
{
    __shared__ float xs[BLK_ROWS][SNN_N];

    const int tid  = threadIdx.x;
    const int lane = tid & 63;
    const int wave = tid >> 6;
    const int row0 = blockIdx.x * BLK_ROWS;

    // Stage 32 x-rows (32 KB, contiguous) : 8192 floats = 2048 float4.
    {
        const float4* x4  = reinterpret_cast<const float4*>(x + (size_t)row0 * SNN_N);
        float4*       xs4 = reinterpret_cast<float4*>(&xs[0][0]);
#pragma unroll
        for (int i = 0; i < 8; ++i) xs4[tid + i * 256] = x4[tid + i * 256];
    }
    __syncthreads();

    // Wave handles rows row0+8*wave .. +7; lane owns cols 4*lane..4*lane+3.
    const int grow0 = row0 + wave * 8;
    const float4* wt4 = reinterpret_cast<const float4*>(WT);   // [k][64 float4]
    const float4* xs4 = reinterpret_cast<const float4*>(&xs[0][0]);
    const int xbase = wave * 8 * 64;   // float4 index of this wave's first row

    float acc[8][4];
#pragma unroll
    for (int r = 0; r < 8; ++r)
#pragma unroll
        for (int c = 0; c < 4; ++c) acc[r][c] = 0.0f;

    // Prefetch iter 0: W_T rows k=0..3, this lane's 16 B (coalesced).
    float4 wcur0 = wt4[0 * 64 + lane];
    float4 wcur1 = wt4[1 * 64 + lane];
    float4 wcur2 = wt4[2 * 64 + lane];
    float4 wcur3 = wt4[3 * 64 + lane];
    float4 xcur[8];
#pragma unroll
    for (int r = 0; r < 8; ++r) xcur[r] = xs4[xbase + r * 64 + 0];

    float* const wfill = out + (size_t)grow0 * SNN_ROW;  // wave's first out row
    const floatx4 z = {0.f, 0.f, 0.f, 0.f};

    for (int i = 0; i < 64; ++i) {
        // ---- prefetch next iteration (wrap at end; redundant last loads) ----
        const int ip = (i + 1) & 63;
        float4 wnx0 = wt4[(ip * 4 + 0) * 64 + lane];
        float4 wnx1 = wt4[(ip * 4 + 1) * 64 + lane];
        float4 wnx2 = wt4[(ip * 4 + 2) * 64 + lane];
        float4 wnx3 = wt4[(ip * 4 + 3) * 64 + lane];
        float4 xnxt[8];
#pragma unroll
        for (int r = 0; r < 8; ++r) xnxt[r] = xs4[xbase + r * 64 + ip];

        // ---- interleaved zero-fill: 4 nt stores (behind the loads above) ----
        // Wave fill region = 8 rows x 8192 floats; float4 idx = (i*4+j)*64+lane.
#pragma unroll
        for (int j = 0; j < 4; ++j) {
            const int fidx = ((i * 4 + j) << 6) + lane;
            const int rl   = fidx >> 11;          // 2048 float4 per row
            const int c4   = fidx & 2047;
            __builtin_nontemporal_store(
                z, reinterpret_cast<floatx4*>(wfill + rl * SNN_ROW + SNN_N + (c4 << 2)));
        }

        // ---- compute iter i: 128 FMAs ----
#pragma unroll
        for (int r = 0; r < 8; ++r) {
            const float4 xr = xcur[r];
            acc[r][0] = fmaf(xr.x, wcur0.x, acc[r][0]);
            acc[r][1] = fmaf(xr.x, wcur0.y, acc[r][1]);
            acc[r][2] = fmaf(xr.x, wcur0.z, acc[r][2]);
            acc[r][3] = fmaf(xr.x, wcur0.w, acc[r][3]);
            acc[r][0] = fmaf(xr.y, wcur1.x, acc[r][0]);
            acc[r][1] = fmaf(xr.y, wcur1.y, acc[r][1]);
            acc[r][2] = fmaf(xr.y, wcur1.z, acc[r][2]);
            acc[r][3] = fmaf(xr.y, wcur1.w, acc[r][3]);
            acc[r][0] = fmaf(xr.z, wcur2.x, acc[r][0]);
            acc[r][1] = fmaf(xr.z, wcur2.y, acc[r][1]);
            acc[r][2] = fmaf(xr.z, wcur2.z, acc[r][2]);
            acc[r][3] = fmaf(xr.z, wcur2.w, acc[r][3]);
            acc[r][0] = fmaf(xr.w, wcur3.x, acc[r][0]);
            acc[r][1] = fmaf(xr.w, wcur3.y, acc[r][1]);
            acc[r][2] = fmaf(xr.w, wcur3.z, acc[r][2]);
            acc[r][3] = fmaf(xr.w, wcur3.w, acc[r][3]);
        }

        wcur0 = wnx0; wcur1 = wnx1; wcur2 = wnx2; wcur3 = wnx3;
#pragma unroll
        for (int r = 0; r < 8; ++r) xcur[r] = xnxt[r];
    }

    // ---- epilogue: bias, threshold, rare f64 recheck, coalesced spike store ----
    const float4 bb = reinterpret_cast<const float4*>(bias)[lane];
#pragma unroll
    for (int r = 0; r < 8; ++r) {
        float h[4] = {acc[r][0] + bb.x, acc[r][1] + bb.y,
                      acc[r][2] + bb.z, acc[r][3] + bb.w};
        float s[4];
#pragma unroll
        for (int c = 0; c < 4; ++c) {
            if (__builtin_expect(fabsf(h[c] - 1.0f) < 1e-3f, 0)) {
                // Borderline (f32 accum error <= ~6e-5 << 1e-3): f64 recheck.
                const int n = 4 * lane + c;
                double a = (double)bias[n];
                const float* wr = W + (size_t)n * SNN_N;
                for (int k = 0; k < SNN_N; ++k)
                    a += (double)wr[k] * (double)xs[wave * 8 + r][k];
                s[c] = (a > 1.0) ? 1.0f : 0.0f;
            } else {
                s[c] = (h[c] > 1.0f) ? 1.0f : 0.0f;
            }
        }
        const floatx4 sv = {s[0], s[1], s[2], s[3]};
        __builtin_nontemporal_store(
            sv, reinterpret_cast<floatx4*>(out + (size_t)(grow0 + r) * SNN_ROW + (lane << 2)));
    }
}

// ---- Fallback (ws too small): round-2 monolithic kernel (69 us, absmax 0) ----
__global__ __launch_bounds__(256) void polysnn_mono_kernel(
    const float* __restrict__ x, const float* __restrict__ W,
    const float* __restrict__ bias, float* __restrict__ out)
{
    __shared__ float xs[8][SNN_N];
    const int tid = threadIdx.x;
    const int row0 = blockIdx.x * 8;
    {
        const float4* x4  = reinterpret_cast<const float4*>(x + (size_t)row0 * SNN_N);
        float4*       xs4 = reinterpret_cast<float4*>(&xs[0][0]);
        xs4[tid] = x4[tid]; xs4[tid + 256] = x4[tid + 256];
    }
    __syncthreads();
    const float4 zz = make_float4(0.f, 0.f, 0.f, 0.f);
#pragma unroll
    for (int r = 0; r < 8; ++r) {
        float4* o4 = reinterpret_cast<float4*>(out + (size_t)(row0 + r) * SNN_ROW + SNN_N);
#pragma unroll
        for (int i = 0; i < 8; ++i) o4[tid + i * 256] = zz;
    }
    const int n = tid;
    float acc[8];
#pragma unroll
    for (int r = 0; r < 8; ++r) acc[r] = 0.0f;
    const float4* w4  = reinterpret_cast<const float4*>(W + (size_t)n * SNN_N);
    const float4* xs4 = reinterpret_cast<const float4*>(&xs[0][0]);
#pragma unroll 4
    for (int k4 = 0; k4 < SNN_N / 4; ++k4) {
        const float4 w = w4[k4];
#pragma unroll
        for (int r = 0; r < 8; ++r) {
            const float4 xr = xs4[r * 64 + k4];
            acc[r] = fmaf(w.x, xr.x, acc[r]); acc[r] = fmaf(w.y, xr.y, acc[r]);
            acc[r] = fmaf(w.z, xr.z, acc[r]); acc[r] = fmaf(w.w, xr.w, acc[r]);
        }
    }
    const float bn = bias[n];
#pragma unroll
    for (int r = 0; r < 8; ++r) {
        const float h = acc[r] + bn;
        float spike;
        if (__builtin_expect(fabsf(h - 1.0f) < 1e-3f, 0)) {
            double a = (double)bn;
            const float* wr = W + (size_t)n * SNN_N;
            for (int k = 0; k < SNN_N; ++k) a += (double)wr[k] * (double)xs[r][k];
            spike = (a > 1.0) ? 1.0f : 0.0f;
        } else spike = (h > 1.0f) ? 1.0f : 0.0f;
        out[(size_t)(row0 + r) * SNN_ROW + n] = spike;
    }
}

extern "C" void kernel_launch(void* const* d_in, const int* in_sizes, int n_in,
                              void* d_out, int out_size, void* d_ws, size_t ws_size,
                              hipStream_t stream) {
    const float* x     = (const float*)d_in[0];
    const float* W_lin = (const float*)d_in[1];
    const float* b_lin = (const float*)d_in[2];
    // d_in[3] (W_sel) and d_in[4] (b_sel) are dead: spk_mode == 0 identically.
    float* out = (float*)d_out;

    if (ws_size >= (size_t)SNN_N * SNN_N * sizeof(float)) {
        float* WT = (float*)d_ws;
        w_transpose_kernel<<<256, 256, 0, stream>>>(W_lin, WT);
        polysnn_main_kernel<<<SNN_B / BLK_ROWS, 256, 0, stream>>>(x, W_lin, WT, b_lin, out);
    } else {
        polysnn_mono_kernel<<<SNN_B / 8, 256, 0, stream>>>(x, W_lin, b_lin, out);
    }
}

// Round 8
// 72.724 us; speedup vs baseline: 2.0017x; 1.0010x over previous
//
#include <hip/hip_runtime.h>
#include <hip/hip_bf16.h>

// PolymorphicSNN: reference collapses to
//   out[:, :256]     = heaviside(x @ W_lin.T + b_lin - 1.0)
//   out[:, 256:8448] = 0    (spk_mode == 0 identically since reg_out in {0,1})
//
// Cost model (round 3/5/6 post-mortem — role splits all regressed):
//  (1) uncoalesced W loads (lane stride 1 KB = 64 lines/instr)  ~27 us/CU
//  (2) too many LDS broadcast reads (1 col/thread)              ~41 us/CU
//  (3) 268 MB zero-fill drain                                   ~39 us chip
// Fix: pre-transpose W into d_ws -> coalesced 16 B/lane W reads; 8x4
// register blocking (32 rows/block, 256 blocks = 1/CU); zero-fill stores
// interleaved INTO the k-loop behind prefetched W loads (stores never gate
// the compute's vmcnt wait); nontemporal stores keep zeros out of L2.

#define SNN_B 8192
#define SNN_N 256
#define SNN_P 32
#define SNN_ROW (SNN_N * (SNN_P + 1))   // 8448 floats per output row
#define BLK_ROWS 32                     // batch rows per block (8 per wave)

typedef float floatx4 __attribute__((ext_vector_type(4)));

// ---- Pre-pass: W_T[k][n] = W[n][k] (256x256) ----
__global__ __launch_bounds__(256) void w_transpose_kernel(
    const float* __restrict__ W, float* __restrict__ WT)
{
    const int o = blockIdx.x * 256 + threadIdx.x;   // 0..65535, coalesced write
    const int k = o >> 8, n = o & 255;
    WT[o] = W[n * SNN_N + k];
}

// ---- Main: GEMM + spikes + interleaved zero-fill ----
__global__ __launch_bounds__(256) void polysnn_main_kernel(
    const float* __restrict__ x,      // [B, N]
    const float* __restrict__ W,      // [N, N] original (borderline recheck only)
    const float* __restrict__ WT,     // [N, N] transposed: WT[k][n]
    const float* __restrict__ bias,   // [N]
    float* __restrict__ out)          // [B, 8448]
{
    __shared__ float xs[BLK_ROWS][SNN_N];

    const int tid  = threadIdx.x;
    const int lane = tid & 63;
    const int wave = tid >> 6;
    const int row0 = blockIdx.x * BLK_ROWS;

    // Stage 32 x-rows (32 KB, contiguous) : 8192 floats = 2048 float4.
    {
        const float4* x4  = reinterpret_cast<const float4*>(x + (size_t)row0 * SNN_N);
        float4*       xs4 = reinterpret_cast<float4*>(&xs[0][0]);
#pragma unroll
        for (int i = 0; i < 8; ++i) xs4[tid + i * 256] = x4[tid + i * 256];
    }
    __syncthreads();

    // Wave handles rows row0+8*wave .. +7; lane owns cols 4*lane..4*lane+3.
    const int grow0 = row0 + wave * 8;
    const float4* wt4 = reinterpret_cast<const float4*>(WT);   // [k][64 float4]
    const float4* xs4 = reinterpret_cast<const float4*>(&xs[0][0]);
    const int xbase = wave * 8 * 64;   // float4 index of this wave's first row

    float acc[8][4];
#pragma unroll
    for (int r = 0; r < 8; ++r)
#pragma unroll
        for (int c = 0; c < 4; ++c) acc[r][c] = 0.0f;

    // Prefetch iter 0: W_T rows k=0..3, this lane's 16 B (coalesced).
    float4 wcur0 = wt4[0 * 64 + lane];
    float4 wcur1 = wt4[1 * 64 + lane];
    float4 wcur2 = wt4[2 * 64 + lane];
    float4 wcur3 = wt4[3 * 64 + lane];
    float4 xcur[8];
#pragma unroll
    for (int r = 0; r < 8; ++r) xcur[r] = xs4[xbase + r * 64 + 0];

    float* const wfill = out + (size_t)grow0 * SNN_ROW;  // wave's first out row
    const floatx4 z = {0.f, 0.f, 0.f, 0.f};

    for (int i = 0; i < 64; ++i) {
        // ---- prefetch next iteration (wrap at end; redundant last loads) ----
        const int ip = (i + 1) & 63;
        float4 wnx0 = wt4[(ip * 4 + 0) * 64 + lane];
        float4 wnx1 = wt4[(ip * 4 + 1) * 64 + lane];
        float4 wnx2 = wt4[(ip * 4 + 2) * 64 + lane];
        float4 wnx3 = wt4[(ip * 4 + 3) * 64 + lane];
        float4 xnxt[8];
#pragma unroll
        for (int r = 0; r < 8; ++r) xnxt[r] = xs4[xbase + r * 64 + ip];

        // ---- interleaved zero-fill: 4 nt stores (behind the loads above) ----
        // Wave fill region = 8 rows x 8192 floats; float4 idx = (i*4+j)*64+lane.
#pragma unroll
        for (int j = 0; j < 4; ++j) {
            const int fidx = ((i * 4 + j) << 6) + lane;
            const int rl   = fidx >> 11;          // 2048 float4 per row
            const int c4   = fidx & 2047;
            __builtin_nontemporal_store(
                z, reinterpret_cast<floatx4*>(wfill + rl * SNN_ROW + SNN_N + (c4 << 2)));
        }

        // ---- compute iter i: 128 FMAs ----
#pragma unroll
        for (int r = 0; r < 8; ++r) {
            const float4 xr = xcur[r];
            acc[r][0] = fmaf(xr.x, wcur0.x, acc[r][0]);
            acc[r][1] = fmaf(xr.x, wcur0.y, acc[r][1]);
            acc[r][2] = fmaf(xr.x, wcur0.z, acc[r][2]);
            acc[r][3] = fmaf(xr.x, wcur0.w, acc[r][3]);
            acc[r][0] = fmaf(xr.y, wcur1.x, acc[r][0]);
            acc[r][1] = fmaf(xr.y, wcur1.y, acc[r][1]);
            acc[r][2] = fmaf(xr.y, wcur1.z, acc[r][2]);
            acc[r][3] = fmaf(xr.y, wcur1.w, acc[r][3]);
            acc[r][0] = fmaf(xr.z, wcur2.x, acc[r][0]);
            acc[r][1] = fmaf(xr.z, wcur2.y, acc[r][1]);
            acc[r][2] = fmaf(xr.z, wcur2.z, acc[r][2]);
            acc[r][3] = fmaf(xr.z, wcur2.w, acc[r][3]);
            acc[r][0] = fmaf(xr.w, wcur3.x, acc[r][0]);
            acc[r][1] = fmaf(xr.w, wcur3.y, acc[r][1]);
            acc[r][2] = fmaf(xr.w, wcur3.z, acc[r][2]);
            acc[r][3] = fmaf(xr.w, wcur3.w, acc[r][3]);
        }

        wcur0 = wnx0; wcur1 = wnx1; wcur2 = wnx2; wcur3 = wnx3;
#pragma unroll
        for (int r = 0; r < 8; ++r) xcur[r] = xnxt[r];
    }

    // ---- epilogue: bias, threshold, rare f64 recheck, coalesced spike store ----
    const float4 bb = reinterpret_cast<const float4*>(bias)[lane];
#pragma unroll
    for (int r = 0; r < 8; ++r) {
        float h[4] = {acc[r][0] + bb.x, acc[r][1] + bb.y,
                      acc[r][2] + bb.z, acc[r][3] + bb.w};
        float s[4];
#pragma unroll
        for (int c = 0; c < 4; ++c) {
            if (__builtin_expect(fabsf(h[c] - 1.0f) < 1e-3f, 0)) {
                // Borderline (f32 accum error <= ~6e-5 << 1e-3): f64 recheck.
                const int n = 4 * lane + c;
                double a = (double)bias[n];
                const float* wr = W + (size_t)n * SNN_N;
                for (int k = 0; k < SNN_N; ++k)
                    a += (double)wr[k] * (double)xs[wave * 8 + r][k];
                s[c] = (a > 1.0) ? 1.0f : 0.0f;
            } else {
                s[c] = (h[c] > 1.0f) ? 1.0f : 0.0f;
            }
        }
        const floatx4 sv = {s[0], s[1], s[2], s[3]};
        __builtin_nontemporal_store(
            sv, reinterpret_cast<floatx4*>(out + (size_t)(grow0 + r) * SNN_ROW + (lane << 2)));
    }
}

// ---- Fallback (ws too small): round-2 monolithic kernel (69 us, absmax 0) ----
__global__ __launch_bounds__(256) void polysnn_mono_kernel(
    const float* __restrict__ x, const float* __restrict__ W,
    const float* __restrict__ bias, float* __restrict__ out)
{
    __shared__ float xs[8][SNN_N];
    const int tid = threadIdx.x;
    const int row0 = blockIdx.x * 8;
    {
        const float4* x4  = reinterpret_cast<const float4*>(x + (size_t)row0 * SNN_N);
        float4*       xs4 = reinterpret_cast<float4*>(&xs[0][0]);
        xs4[tid] = x4[tid]; xs4[tid + 256] = x4[tid + 256];
    }
    __syncthreads();
    const float4 zz = make_float4(0.f, 0.f, 0.f, 0.f);
#pragma unroll
    for (int r = 0; r < 8; ++r) {
        float4* o4 = reinterpret_cast<float4*>(out + (size_t)(row0 + r) * SNN_ROW + SNN_N);
#pragma unroll
        for (int i = 0; i < 8; ++i) o4[tid + i * 256] = zz;
    }
    const int n = tid;
    float acc[8];
#pragma unroll
    for (int r = 0; r < 8; ++r) acc[r] = 0.0f;
    const float4* w4  = reinterpret_cast<const float4*>(W + (size_t)n * SNN_N);
    const float4* xs4 = reinterpret_cast<const float4*>(&xs[0][0]);
#pragma unroll 4
    for (int k4 = 0; k4 < SNN_N / 4; ++k4) {
        const float4 w = w4[k4];
#pragma unroll
        for (int r = 0; r < 8; ++r) {
            const float4 xr = xs4[r * 64 + k4];
            acc[r] = fmaf(w.x, xr.x, acc[r]); acc[r] = fmaf(w.y, xr.y, acc[r]);
            acc[r] = fmaf(w.z, xr.z, acc[r]); acc[r] = fmaf(w.w, xr.w, acc[r]);
        }
    }
    const float bn = bias[n];
#pragma unroll
    for (int r = 0; r < 8; ++r) {
        const float h = acc[r] + bn;
        float spike;
        if (__builtin_expect(fabsf(h - 1.0f) < 1e-3f, 0)) {
            double a = (double)bn;
            const float* wr = W + (size_t)n * SNN_N;
            for (int k = 0; k < SNN_N; ++k) a += (double)wr[k] * (double)xs[r][k];
            spike = (a > 1.0) ? 1.0f : 0.0f;
        } else spike = (h > 1.0f) ? 1.0f : 0.0f;
        out[(size_t)(row0 + r) * SNN_ROW + n] = spike;
    }
}

extern "C" void kernel_launch(void* const* d_in, const int* in_sizes, int n_in,
                              void* d_out, int out_size, void* d_ws, size_t ws_size,
                              hipStream_t stream) {
    const float* x     = (const float*)d_in[0];
    const float* W_lin = (const float*)d_in[1];
    const float* b_lin = (const float*)d_in[2];
    // d_in[3] (W_sel) and d_in[4] (b_sel) are dead: spk_mode == 0 identically.
    float* out = (float*)d_out;

    if (ws_size >= (size_t)SNN_N * SNN_N * sizeof(float)) {
        float* WT = (float*)d_ws;
        w_transpose_kernel<<<256, 256, 0, stream>>>(W_lin, WT);
        polysnn_main_kernel<<<SNN_B / BLK_ROWS, 256, 0, stream>>>(x, W_lin, WT, b_lin, out);
    } else {
        polysnn_mono_kernel<<<SNN_B / 8, 256, 0, stream>>>(x, W_lin, b_lin, out);
    }
}

// Round 9
// 59.860 us; speedup vs baseline: 2.4319x; 1.2149x over previous
//
#include <hip/hip_runtime.h>
#include <hip/hip_bf16.h>

// PolymorphicSNN: reference collapses to
//   out[:, :256]     = heaviside(x @ W_lin.T + b_lin - 1.0)
//   out[:, 256:8448] = 0    (spk_mode == 0 identically since reg_out in {0,1})
//
// Round-8 post-mortem: fixing W coalescing + LDS pressure changed nothing
// (69 -> 72.7). 277 MB / 72.7 us = 3.9 TB/s == suspected nontemporal-store
// ceiling; the harness's own fill (regular cached stores) runs 6.9 TB/s.
// This round: IDENTICAL structure to round 8 but regular stores everywhere
// (single-variable A/B on the store path), and 512 blocks (8 waves/CU) so
// store issue gaps during FMA bursts are covered by more waves.

#define SNN_B 8192
#define SNN_N 256
#define SNN_P 32
#define SNN_ROW (SNN_N * (SNN_P + 1))   // 8448 floats per output row
#define BLK_ROWS 16                     // batch rows per block (4 per wave)

// ---- Pre-pass: W_T[k][n] = W[n][k] (256x256) ----
__global__ __launch_bounds__(256) void w_transpose_kernel(
    const float* __restrict__ W, float* __restrict__ WT)
{
    const int o = blockIdx.x * 256 + threadIdx.x;   // coalesced write
    const int k = o >> 8, n = o & 255;
    WT[o] = W[n * SNN_N + k];
}

// ---- Main: GEMM + spikes + interleaved zero-fill (regular stores) ----
__global__ __launch_bounds__(256) void polysnn_main_kernel(
    const float* __restrict__ x,      // [B, N]
    const float* __restrict__ W,      // [N, N] original (borderline recheck only)
    const float* __restrict__ WT,     // [N, N] transposed: WT[k][n]
    const float* __restrict__ bias,   // [N]
    float* __restrict__ out)          // [B, 8448]
{
    __shared__ float xs[BLK_ROWS][SNN_N];

    const int tid  = threadIdx.x;
    const int lane = tid & 63;
    const int wave = tid >> 6;
    const int row0 = blockIdx.x * BLK_ROWS;

    // Stage 16 x-rows (16 KB, contiguous): 4096 floats = 1024 float4.
    {
        const float4* x4  = reinterpret_cast<const float4*>(x + (size_t)row0 * SNN_N);
        float4*       xs4 = reinterpret_cast<float4*>(&xs[0][0]);
#pragma unroll
        for (int i = 0; i < 4; ++i) xs4[tid + i * 256] = x4[tid + i * 256];
    }
    __syncthreads();

    // Wave handles rows row0 + 4*wave .. +3; lane owns cols 4*lane..4*lane+3.
    const int grow0 = row0 + wave * 4;
    const float4* wt4 = reinterpret_cast<const float4*>(WT);   // [k][64 float4]
    const float4* xs4 = reinterpret_cast<const float4*>(&xs[0][0]);
    const int xbase = wave * 4 * 64;   // float4 index of this wave's first row

    float acc[4][4];
#pragma unroll
    for (int r = 0; r < 4; ++r)
#pragma unroll
        for (int c = 0; c < 4; ++c) acc[r][c] = 0.0f;

    // Prefetch iter 0: W_T rows k=0..3, this lane's 16 B (coalesced).
    float4 wcur0 = wt4[0 * 64 + lane];
    float4 wcur1 = wt4[1 * 64 + lane];
    float4 wcur2 = wt4[2 * 64 + lane];
    float4 wcur3 = wt4[3 * 64 + lane];
    float4 xcur[4];
#pragma unroll
    for (int r = 0; r < 4; ++r) xcur[r] = xs4[xbase + r * 64 + 0];

    float* const wfill = out + (size_t)grow0 * SNN_ROW;  // wave's first out row
    const float4 z = make_float4(0.f, 0.f, 0.f, 0.f);

    for (int i = 0; i < 64; ++i) {
        // ---- prefetch next iteration (wrap at end; redundant last loads) ----
        const int ip = (i + 1) & 63;
        float4 wnx0 = wt4[(ip * 4 + 0) * 64 + lane];
        float4 wnx1 = wt4[(ip * 4 + 1) * 64 + lane];
        float4 wnx2 = wt4[(ip * 4 + 2) * 64 + lane];
        float4 wnx3 = wt4[(ip * 4 + 3) * 64 + lane];
        float4 xnxt[4];
#pragma unroll
        for (int r = 0; r < 4; ++r) xnxt[r] = xs4[xbase + r * 64 + ip];

        // ---- interleaved zero-fill: 2 REGULAR stores (behind the loads) ----
        // Wave fill region = 4 rows x 8192 floats = 8192 float4;
        // fidx = (i*2 + j)*64 + lane; 2048 float4 per row.
#pragma unroll
        for (int j = 0; j < 2; ++j) {
            const int fidx = ((i * 2 + j) << 6) + lane;
            const int rl   = fidx >> 11;
            const int c4   = fidx & 2047;
            *reinterpret_cast<float4*>(wfill + rl * SNN_ROW + SNN_N + (c4 << 2)) = z;
        }

        // ---- compute iter i: 64 FMAs ----
#pragma unroll
        for (int r = 0; r < 4; ++r) {
            const float4 xr = xcur[r];
            acc[r][0] = fmaf(xr.x, wcur0.x, acc[r][0]);
            acc[r][1] = fmaf(xr.x, wcur0.y, acc[r][1]);
            acc[r][2] = fmaf(xr.x, wcur0.z, acc[r][2]);
            acc[r][3] = fmaf(xr.x, wcur0.w, acc[r][3]);
            acc[r][0] = fmaf(xr.y, wcur1.x, acc[r][0]);
            acc[r][1] = fmaf(xr.y, wcur1.y, acc[r][1]);
            acc[r][2] = fmaf(xr.y, wcur1.z, acc[r][2]);
            acc[r][3] = fmaf(xr.y, wcur1.w, acc[r][3]);
            acc[r][0] = fmaf(xr.z, wcur2.x, acc[r][0]);
            acc[r][1] = fmaf(xr.z, wcur2.y, acc[r][1]);
            acc[r][2] = fmaf(xr.z, wcur2.z, acc[r][2]);
            acc[r][3] = fmaf(xr.z, wcur2.w, acc[r][3]);
            acc[r][0] = fmaf(xr.w, wcur3.x, acc[r][0]);
            acc[r][1] = fmaf(xr.w, wcur3.y, acc[r][1]);
            acc[r][2] = fmaf(xr.w, wcur3.z, acc[r][2]);
            acc[r][3] = fmaf(xr.w, wcur3.w, acc[r][3]);
        }

        wcur0 = wnx0; wcur1 = wnx1; wcur2 = wnx2; wcur3 = wnx3;
#pragma unroll
        for (int r = 0; r < 4; ++r) xcur[r] = xnxt[r];
    }

    // ---- epilogue: bias, threshold, rare f64 recheck, coalesced spike store ----
    const float4 bb = reinterpret_cast<const float4*>(bias)[lane];
#pragma unroll
    for (int r = 0; r < 4; ++r) {
        float h[4] = {acc[r][0] + bb.x, acc[r][1] + bb.y,
                      acc[r][2] + bb.z, acc[r][3] + bb.w};
        float s[4];
#pragma unroll
        for (int c = 0; c < 4; ++c) {
            if (__builtin_expect(fabsf(h[c] - 1.0f) < 1e-3f, 0)) {
                // Borderline (f32 accum error <= ~6e-5 << 1e-3): f64 recheck.
                const int n = 4 * lane + c;
                double a = (double)bias[n];
                const float* wr = W + (size_t)n * SNN_N;
                for (int k = 0; k < SNN_N; ++k)
                    a += (double)wr[k] * (double)xs[wave * 4 + r][k];
                s[c] = (a > 1.0) ? 1.0f : 0.0f;
            } else {
                s[c] = (h[c] > 1.0f) ? 1.0f : 0.0f;
            }
        }
        *reinterpret_cast<float4*>(out + (size_t)(grow0 + r) * SNN_ROW + (lane << 2))
            = make_float4(s[0], s[1], s[2], s[3]);
    }
}

// ---- Fallback (ws too small): round-2 monolithic kernel (69 us, absmax 0) ----
__global__ __launch_bounds__(256) void polysnn_mono_kernel(
    const float* __restrict__ x, const float* __restrict__ W,
    const float* __restrict__ bias, float* __restrict__ out)
{
    __shared__ float xs[8][SNN_N];
    const int tid = threadIdx.x;
    const int row0 = blockIdx.x * 8;
    {
        const float4* x4  = reinterpret_cast<const float4*>(x + (size_t)row0 * SNN_N);
        float4*       xs4 = reinterpret_cast<float4*>(&xs[0][0]);
        xs4[tid] = x4[tid]; xs4[tid + 256] = x4[tid + 256];
    }
    __syncthreads();
    const float4 zz = make_float4(0.f, 0.f, 0.f, 0.f);
#pragma unroll
    for (int r = 0; r < 8; ++r) {
        float4* o4 = reinterpret_cast<float4*>(out + (size_t)(row0 + r) * SNN_ROW + SNN_N);
#pragma unroll
        for (int i = 0; i < 8; ++i) o4[tid + i * 256] = zz;
    }
    const int n = tid;
    float acc[8];
#pragma unroll
    for (int r = 0; r < 8; ++r) acc[r] = 0.0f;
    const float4* w4  = reinterpret_cast<const float4*>(W + (size_t)n * SNN_N);
    const float4* xs4 = reinterpret_cast<const float4*>(&xs[0][0]);
#pragma unroll 4
    for (int k4 = 0; k4 < SNN_N / 4; ++k4) {
        const float4 w = w4[k4];
#pragma unroll
        for (int r = 0; r < 8; ++r) {
            const float4 xr = xs4[r * 64 + k4];
            acc[r] = fmaf(w.x, xr.x, acc[r]); acc[r] = fmaf(w.y, xr.y, acc[r]);
            acc[r] = fmaf(w.z, xr.z, acc[r]); acc[r] = fmaf(w.w, xr.w, acc[r]);
        }
    }
    const float bn = bias[n];
#pragma unroll
    for (int r = 0; r < 8; ++r) {
        const float h = acc[r] + bn;
        float spike;
        if (__builtin_expect(fabsf(h - 1.0f) < 1e-3f, 0)) {
            double a = (double)bn;
            const float* wr = W + (size_t)n * SNN_N;
            for (int k = 0; k < SNN_N; ++k) a += (double)wr[k] * (double)xs[r][k];
            spike = (a > 1.0) ? 1.0f : 0.0f;
        } else spike = (h > 1.0f) ? 1.0f : 0.0f;
        out[(size_t)(row0 + r) * SNN_ROW + n] = spike;
    }
}

extern "C" void kernel_launch(void* const* d_in, const int* in_sizes, int n_in,
                              void* d_out, int out_size, void* d_ws, size_t ws_size,
                              hipStream_t stream) {
    const float* x     = (const float*)d_in[0];
    const float* W_lin = (const float*)d_in[1];
    const float* b_lin = (const float*)d_in[2];
    // d_in[3] (W_sel) and d_in[4] (b_sel) are dead: spk_mode == 0 identically.
    float* out = (float*)d_out;

    if (ws_size >= (size_t)SNN_N * SNN_N * sizeof(float)) {
        float* WT = (float*)d_ws;
        w_transpose_kernel<<<256, 256, 0, stream>>>(W_lin, WT);
        polysnn_main_kernel<<<SNN_B / BLK_ROWS, 256, 0, stream>>>(x, W_lin, WT, b_lin, out);
    } else {
        polysnn_mono_kernel<<<SNN_B / 8, 256, 0, stream>>>(x, W_lin, b_lin, out);
    }
}